// Round 1
// baseline (85.898 us; speedup 1.0000x reference)
//
#include <hip/hip_runtime.h>
#include <math.h>

// Problem constants (from reference)
#define SPIN 365
#define TRAINL 200000

#define THREADS 256
#define ITEMS 4
#define CHUNK (THREADS * ITEMS)  // 1024 elements per block

// B = 262144 -> G = 256 blocks. k_phase2 assumes G <= THREADS.

struct Sc { float oo, oogw, ol1, b0, wb2; };

__device__ __forceinline__ Sc get_sc(const float* w0, const float* w1,
                                     const float* w2, const float* w3,
                                     const float* b0p, const float* wb2p) {
  float e_om = expf(w0[0]);
  float e_gw = expf(w1[0]);
  float e_lm = expf(w2[0]);
  float e_fm = expf(w3[0]);
  float denom = e_om + e_gw + e_lm + e_fm;
  Sc s;
  s.oo   = e_om / denom;
  s.oogw = e_gw / denom;
  s.ol1  = e_lm / denom;
  s.b0   = b0p[0];
  s.wb2  = wb2p[0];
  return s;
}

__device__ __forceinline__ float sigm(float z) { return 1.0f / (1.0f + expf(-z)); }

// ws layout (floats):
// [0,G)     block aggregate P
// [G,2G)    block aggregate Q
// [2G,3G)   block partial sum   of y_obs[SPIN:TRAINL]
// [3G,4G)   block partial sumsq of y_obs[SPIN:TRAINL]
// [4G,5G)   block carry C_g  (written by k_phase2)
// [5G]      obsstd scalar     (written by k_phase2)

extern "C" __global__ __launch_bounds__(THREADS) void k_phase1(
    const float* __restrict__ x, const float* __restrict__ y,
    const int* __restrict__ tlp,
    const float* __restrict__ w0, const float* __restrict__ w1,
    const float* __restrict__ w2, const float* __restrict__ w3,
    const float* __restrict__ b0p, const float* __restrict__ wb2p,
    float* __restrict__ out, float* __restrict__ ws, int B, int G)
{
  const int g = blockIdx.x, tid = threadIdx.x;
  const int tl = tlp[0];
  const Sc sc = get_sc(w0, w1, w2, w3, b0p, wb2p);
  const int base = g * CHUNK + tid * ITEMS;
  const bool full = (base + ITEMS) <= B;

  float u1v[ITEMS], u2v[ITEMS];
  if (full) {
    float4 a = *(const float4*)(x + 2 * (size_t)base);
    float4 b = *(const float4*)(x + 2 * (size_t)base + 4);
    u1v[0]=a.x; u2v[0]=a.y; u1v[1]=a.z; u2v[1]=a.w;
    u1v[2]=b.x; u2v[2]=b.y; u1v[3]=b.z; u2v[3]=b.w;
  } else {
    for (int j = 0; j < ITEMS; j++) {
      int p = base + j;
      u1v[j] = (p < B) ? x[2*(size_t)p]     : 0.f;
      u2v[j] = (p < B) ? x[2*(size_t)p + 1] : 0.f;
    }
  }

  float P = 1.f, Q = 0.f;
  float voo[ITEMS], vgw[ITEMS], vol[ITEMS], vf[ITEMS];
  for (int j = 0; j < ITEMS; j++) {
    int p = base + j;
    float ol = sc.ol1 * sigm(sc.b0 + (u2v[j] - 2.9086f) / 1.898f * sc.wb2);
    float f  = 1.0f - sc.oo - ol - sc.oogw;
    bool act = (p >= tl) && (p < B);
    voo[j] = act ? sc.oo   : 0.f;
    vgw[j] = act ? sc.oogw : 0.f;
    vol[j] = act ? ol      : 0.f;
    vf[j]  = act ? f       : 0.f;
    if (act) { Q = f * Q + u1v[j]; P *= f; }
  }

  // c-independent outputs
  if (full) {
    *(float4*)(out + 4*(size_t)B + base) = make_float4(0,0,0,0);             // bp_n
    *(float4*)(out + 5*(size_t)B + base) = make_float4(0,0,0,0);             // gate_ib
    *(float4*)(out + 6*(size_t)B + base) = make_float4(voo[0],voo[1],voo[2],voo[3]); // gate_oo
    *(float4*)(out + 7*(size_t)B + base) = make_float4(vgw[0],vgw[1],vgw[2],vgw[3]); // gate_oogw
    *(float4*)(out + 8*(size_t)B + base) = make_float4(vol[0],vol[1],vol[2],vol[3]); // gate_ol
    *(float4*)(out + 9*(size_t)B + base) = make_float4(vf[0],vf[1],vf[2],vf[3]);     // gate_f
  } else {
    for (int j = 0; j < ITEMS; j++) {
      int p = base + j;
      if (p < B) {
        out[4*(size_t)B+p] = 0.f;    out[5*(size_t)B+p] = 0.f;
        out[6*(size_t)B+p] = voo[j]; out[7*(size_t)B+p] = vgw[j];
        out[8*(size_t)B+p] = vol[j]; out[9*(size_t)B+p] = vf[j];
      }
    }
  }

  // block-level inclusive scan of affine pairs (Hillis-Steele in LDS)
  __shared__ float sA[THREADS], sB[THREADS];
  sA[tid] = P; sB[tid] = Q;
  __syncthreads();
  for (int off = 1; off < THREADS; off <<= 1) {
    float a = sA[tid], b = sB[tid];
    float pa = 1.f, pb = 0.f;
    if (tid >= off) { pa = sA[tid - off]; pb = sB[tid - off]; }
    __syncthreads();
    sA[tid] = pa * a;
    sB[tid] = a * pb + b;
    __syncthreads();
  }
  if (tid == THREADS - 1) { ws[g] = sA[tid]; ws[G + g] = sB[tid]; }

  // y_obs partial sums for std
  float s = 0.f, ss = 0.f;
  if (base < TRAINL) {
    if (full) {
      float4 yv = *(const float4*)(y + base);
      float vv[4] = { yv.x, yv.y, yv.z, yv.w };
      for (int j = 0; j < ITEMS; j++) {
        int p = base + j;
        if (p >= SPIN && p < TRAINL) { s += vv[j]; ss += vv[j]*vv[j]; }
      }
    } else {
      for (int j = 0; j < ITEMS; j++) {
        int p = base + j;
        if (p >= SPIN && p < TRAINL && p < B) { float v = y[p]; s += v; ss += v*v; }
      }
    }
  }
  __syncthreads();
  sA[tid] = s; sB[tid] = ss;
  __syncthreads();
  for (int off = THREADS/2; off > 0; off >>= 1) {
    if (tid < off) { sA[tid] += sA[tid + off]; sB[tid] += sB[tid + off]; }
    __syncthreads();
  }
  if (tid == 0) { ws[2*G + g] = sA[0]; ws[3*G + g] = sB[0]; }
}

extern "C" __global__ __launch_bounds__(THREADS) void k_phase2(
    float* __restrict__ ws, int G)
{
  const int tid = threadIdx.x;
  __shared__ float sA[THREADS], sB[THREADS];
  float a = (tid < G) ? ws[tid]     : 1.f;
  float b = (tid < G) ? ws[G + tid] : 0.f;
  sA[tid] = a; sB[tid] = b;
  __syncthreads();
  for (int off = 1; off < THREADS; off <<= 1) {
    float ca = sA[tid], cb = sB[tid];
    float pa = 1.f, pb = 0.f;
    if (tid >= off) { pa = sA[tid - off]; pb = sB[tid - off]; }
    __syncthreads();
    sA[tid] = pa * ca;
    sB[tid] = ca * pb + cb;
    __syncthreads();
  }
  // carry into block g = Q of composition of blocks [0,g) applied to c=0
  if (tid < G) ws[4*G + tid] = (tid == 0) ? 0.f : sB[tid - 1];
  __syncthreads();

  // reduce y partials -> obsstd (ddof=1)
  float s  = (tid < G) ? ws[2*G + tid] : 0.f;
  float ss = (tid < G) ? ws[3*G + tid] : 0.f;
  sA[tid] = s; sB[tid] = ss;
  __syncthreads();
  for (int off = THREADS/2; off > 0; off >>= 1) {
    if (tid < off) { sA[tid] += sA[tid + off]; sB[tid] += sB[tid + off]; }
    __syncthreads();
  }
  if (tid == 0) {
    float n = (float)(TRAINL - SPIN);
    float S = sA[0], SS = sB[0];
    float mean = S / n;
    float var = (SS - n * mean * mean) / (n - 1.0f);
    ws[5*G] = sqrtf(fmaxf(var, 0.f));
  }
}

extern "C" __global__ __launch_bounds__(THREADS) void k_phase3(
    const float* __restrict__ x, const int* __restrict__ tlp,
    const float* __restrict__ w0, const float* __restrict__ w1,
    const float* __restrict__ w2, const float* __restrict__ w3,
    const float* __restrict__ b0p, const float* __restrict__ wb2p,
    float* __restrict__ out, const float* __restrict__ ws, int B, int G)
{
  const int g = blockIdx.x, tid = threadIdx.x;
  const int tl = tlp[0];
  const Sc sc = get_sc(w0, w1, w2, w3, b0p, wb2p);
  const int base = g * CHUNK + tid * ITEMS;
  const bool full = (base + ITEMS) <= B;

  float u1v[ITEMS], u2v[ITEMS];
  if (full) {
    float4 a = *(const float4*)(x + 2 * (size_t)base);
    float4 b = *(const float4*)(x + 2 * (size_t)base + 4);
    u1v[0]=a.x; u2v[0]=a.y; u1v[1]=a.z; u2v[1]=a.w;
    u1v[2]=b.x; u2v[2]=b.y; u1v[3]=b.z; u2v[3]=b.w;
  } else {
    for (int j = 0; j < ITEMS; j++) {
      int p = base + j;
      u1v[j] = (p < B) ? x[2*(size_t)p]     : 0.f;
      u2v[j] = (p < B) ? x[2*(size_t)p + 1] : 0.f;
    }
  }

  float P = 1.f, Q = 0.f;
  float fv[ITEMS], olv[ITEMS];
  for (int j = 0; j < ITEMS; j++) {
    int p = base + j;
    float ol = sc.ol1 * sigm(sc.b0 + (u2v[j] - 2.9086f) / 1.898f * sc.wb2);
    float f  = 1.0f - sc.oo - ol - sc.oogw;
    bool act = (p >= tl) && (p < B);
    olv[j] = ol; fv[j] = f;
    if (act) { Q = f * Q + u1v[j]; P *= f; }
  }

  __shared__ float sA[THREADS], sB[THREADS];
  sA[tid] = P; sB[tid] = Q;
  __syncthreads();
  for (int off = 1; off < THREADS; off <<= 1) {
    float a = sA[tid], b = sB[tid];
    float pa = 1.f, pb = 0.f;
    if (tid >= off) { pa = sA[tid - off]; pb = sB[tid - off]; }
    __syncthreads();
    sA[tid] = pa * a;
    sB[tid] = a * pb + b;
    __syncthreads();
  }
  float Ae = 1.f, Be = 0.f;
  if (tid > 0) { Ae = sA[tid - 1]; Be = sB[tid - 1]; }

  const float Cg   = ws[4*G + g];
  const float ostd = ws[5*G];
  float c = Ae * Cg + Be;   // c at this thread's first element

  float vh[ITEMS], vc[ITEMS], vl[ITEMS], vgw[ITEMS], vos[ITEMS];
  for (int j = 0; j < ITEMS; j++) {
    int p = base + j;
    bool act = (p >= tl) && (p < B);
    float c0 = c;                 // c BEFORE this step (scan emits c_prev)
    vh[j]  = sc.oo * c0;
    vc[j]  = c0;
    vl[j]  = olv[j] * c0;
    vgw[j] = sc.oogw * c0;
    vos[j] = act ? ostd : 0.f;
    if (act) { c = fv[j] * c + u1v[j]; }
  }

  if (full) {
    *(float4*)(out + (size_t)base)            = make_float4(vh[0],vh[1],vh[2],vh[3]);   // h_n
    *(float4*)(out + (size_t)B + base)        = make_float4(vc[0],vc[1],vc[2],vc[3]);   // c_n
    *(float4*)(out + 2*(size_t)B + base)      = make_float4(vl[0],vl[1],vl[2],vl[3]);   // l_n
    *(float4*)(out + 3*(size_t)B + base)      = make_float4(vgw[0],vgw[1],vgw[2],vgw[3]); // gw_n
    *(float4*)(out + 12*(size_t)B + base)     = make_float4(vos[0],vos[1],vos[2],vos[3]); // obs_std
    // h_nout: (B,2) row-major interleave [h, obsstd]
    *(float4*)(out + 10*(size_t)B + 2*base)     = make_float4(vh[0],vos[0],vh[1],vos[1]);
    *(float4*)(out + 10*(size_t)B + 2*base + 4) = make_float4(vh[2],vos[2],vh[3],vos[3]);
  } else {
    for (int j = 0; j < ITEMS; j++) {
      int p = base + j;
      if (p < B) {
        out[(size_t)p]            = vh[j];
        out[(size_t)B + p]        = vc[j];
        out[2*(size_t)B + p]      = vl[j];
        out[3*(size_t)B + p]      = vgw[j];
        out[12*(size_t)B + p]     = vos[j];
        out[10*(size_t)B + 2*p]     = vh[j];
        out[10*(size_t)B + 2*p + 1] = vos[j];
      }
    }
  }
}

extern "C" void kernel_launch(void* const* d_in, const int* in_sizes, int n_in,
                              void* d_out, int out_size, void* d_ws, size_t ws_size,
                              hipStream_t stream) {
  const float* x   = (const float*)d_in[0];
  const float* y   = (const float*)d_in[1];
  // d_in[2] = epoch (unused)
  const int*   tl  = (const int*)d_in[3];
  const float* w0  = (const float*)d_in[4];  // weight_r_yom
  const float* w1  = (const float*)d_in[5];  // weight_r_yom_gw
  const float* w2  = (const float*)d_in[6];  // weight_r_ylm
  const float* w3  = (const float*)d_in[7];  // weight_r_yfm
  const float* b0  = (const float*)d_in[8];  // bias_b0_ylm
  const float* wb2 = (const float*)d_in[9];  // weight_b2_ylm

  float* out = (float*)d_out;
  float* ws  = (float*)d_ws;

  const int B = in_sizes[0] / 2;           // x is (B, 1, 2)
  const int G = (B + CHUNK - 1) / CHUNK;   // 256 for B=262144 (k_phase2 needs G<=256)

  k_phase1<<<G, THREADS, 0, stream>>>(x, y, tl, w0, w1, w2, w3, b0, wb2, out, ws, B, G);
  k_phase2<<<1, THREADS, 0, stream>>>(ws, G);
  k_phase3<<<G, THREADS, 0, stream>>>(x, tl, w0, w1, w2, w3, b0, wb2, out, ws, B, G);
}